// Round 10
// baseline (88.899 us; speedup 1.0000x reference)
//
#include <hip/hip_runtime.h>
#include <math.h>

#define BB 16
#define SS 2048
#define NF 330      // monomials deg<=7 in 4 vars
#define NS 495      // power sums deg<=8
#define SPAD 512    // padded per-(b,h) stride in ws (floats)
#define NTILE 31    // ceil(495/16)

struct E4 { unsigned char e0, e1, e2, e3; };

struct Tables {
  E4 se[496];          // sum exponents |beta|<=8, enumeration order
  E4 fe[330];          // feature exponents |alpha|<=7
  float fc[330];       // feature coefficient C_alpha = b_k * mult(alpha) / 2^k
  short sidx[330][5];  // rank of alpha+u_m (m=0..3) and alpha (m=4) in se[]
};

constexpr int T1c(int n){ return n+1; }
constexpr int T2c(int n){ return (n+1)*(n+2)/2; }
constexpr int T3c(int n){ return (n+1)*(n+2)*(n+3)/6; }
constexpr int rank8(int a,int b,int c,int d){
  int r = 0;
  for (int e0=0;e0<a;++e0) r += T3c(8-e0);
  for (int e1=0;e1<b;++e1) r += T2c(8-a-e1);
  for (int e2=0;e2<c;++e2) r += T1c(8-a-b-e2);
  return r + d;
}
constexpr double besselI2(int n){           // I_n(2) via series 1/(m!(m+n)!)
  double t = 1.0;
  for (int i=1;i<=n;++i) t /= (double)i;    // t_0 = 1/n!
  double s = 0.0;
  for (int m=0;m<14;++m){ if (m>0) t /= (double)(m*(m+n)); s += t; }
  return s;
}
constexpr Tables gen(){
  Tables T{};
  // Chebyshev expansion of e^s on [-2,2] -> monomial coeffs b_k of s^k
  double cheb[8] = {};
  for (int n=0;n<8;++n) cheb[n] = (n==0?1.0:2.0)*besselI2(n);
  const int tm[8][8] = {                    // T_n(t) monomial coefficients
    {1,0,0,0,0,0,0,0},{0,1,0,0,0,0,0,0},{-1,0,2,0,0,0,0,0},{0,-3,0,4,0,0,0,0},
    {1,0,-8,0,8,0,0,0},{0,5,0,-20,0,16,0,0},{-1,0,18,0,-48,0,32,0},{0,-7,0,56,0,-112,0,64}};
  double bk[8] = {};
  double p2 = 1.0;
  for (int k=0;k<8;++k){
    double tc = 0.0;
    for (int n=0;n<8;++n) tc += cheb[n]*(double)tm[n][k];
    bk[k] = tc/p2;                          // t = s/2  ->  /2^k
    p2 *= 2.0;
  }
  const double fact[9] = {1,1,2,6,24,120,720,5040,40320};
  { // sums table |beta|<=8
    int idx = 0;
    for (int a=0;a<=8;++a) for (int b=0;b<=8-a;++b) for (int c=0;c<=8-a-b;++c)
      for (int d=0;d<=8-a-b-c;++d){
        T.se[idx].e0=(unsigned char)a; T.se[idx].e1=(unsigned char)b;
        T.se[idx].e2=(unsigned char)c; T.se[idx].e3=(unsigned char)d; ++idx;
      }
  }
  { // feature table |alpha|<=7 with coefficients and sum indices
    int idx = 0;
    for (int a=0;a<=7;++a) for (int b=0;b<=7-a;++b) for (int c=0;c<=7-a-b;++c)
      for (int d=0;d<=7-a-b-c;++d){
        const int k = a+b+c+d;
        const double mult = fact[k]/(fact[a]*fact[b]*fact[c]*fact[d]);
        double pk = 1.0; for (int i=0;i<k;++i) pk *= 2.0;
        T.fe[idx].e0=(unsigned char)a; T.fe[idx].e1=(unsigned char)b;
        T.fe[idx].e2=(unsigned char)c; T.fe[idx].e3=(unsigned char)d;
        T.fc[idx] = (float)(bk[k]*mult/pk);
        T.sidx[idx][0] = (short)rank8(a+1,b,c,d);
        T.sidx[idx][1] = (short)rank8(a,b+1,c,d);
        T.sidx[idx][2] = (short)rank8(a,b,c+1,d);
        T.sidx[idx][3] = (short)rank8(a,b,c,d+1);
        T.sidx[idx][4] = (short)rank8(a,b,c,d);
        ++idx;
      }
  }
  return T;
}
constexpr Tables TAB = gen();

// ---- K1: power sums S_beta = sum_rows q^beta per (b,h), atomicAdd into ws ----
template<int T>
__device__ __forceinline__ void sum_tile(const float4* __restrict__ x4,
                                         float4 th, int b, int h, int t,
                                         float* __restrict__ wsbh){
  float acc[16];
#pragma unroll
  for (int i=0;i<16;++i) acc[i] = 0.f;
  for (int rr=0; rr<8; ++rr){
    const int s = (rr<<8) + t;
    float4 xr = x4[(size_t)(b*SS+s)*2 + h];
    const float q0 = __cosf(xr.x + th.x), q1 = __cosf(xr.y + th.y),
                q2 = __cosf(xr.z + th.z), q3 = __cosf(xr.w + th.w);
    float p0[9], p1[9], p2[9], p3[9];
    p0[0]=1.f; p1[0]=1.f; p2[0]=1.f; p3[0]=1.f;
#pragma unroll
    for (int e=1;e<9;++e){
      p0[e]=p0[e-1]*q0; p1[e]=p1[e-1]*q1; p2[e]=p2[e-1]*q2; p3[e]=p3[e-1]*q3;
    }
#pragma unroll
    for (int i=0;i<16;++i){
      if (T*16+i < NS){
        const E4 e = TAB.se[T*16+i];     // constexpr -> folds after unroll
        acc[i] += p0[e.e0]*p1[e.e1]*p2[e.e2]*p3[e.e3];
      }
    }
  }
  const int lane = (int)(threadIdx.x & 63);
#pragma unroll
  for (int i=0;i<16;++i){
    if (T*16+i < NS){
      float v = acc[i];
#pragma unroll
      for (int st=1; st<64; st<<=1) v += __shfl_xor(v, st, 64);
      if (lane == 0) atomicAdd(wsbh + T*16 + i, v);
    }
  }
}

__global__ __launch_bounds__(256)
void qsum_kernel(const float* __restrict__ x, const float* __restrict__ theta,
                 float* __restrict__ ws){
  const int tile = blockIdx.x & 31;
  if (tile >= NTILE) return;
  const int bh = blockIdx.x >> 5;
  const int b = bh >> 1, h = bh & 1;
  const int t = (int)threadIdx.x;
  const float4 th = ((const float4*)theta)[h];
  const float4* x4 = (const float4*)x;
  float* wsbh = ws + (size_t)bh * SPAD;
  switch(tile){
#define KCASE(n) case n: sum_tile<n>(x4, th, b, h, t, wsbh); break;
    KCASE(0) KCASE(1) KCASE(2) KCASE(3) KCASE(4) KCASE(5) KCASE(6) KCASE(7)
    KCASE(8) KCASE(9) KCASE(10) KCASE(11) KCASE(12) KCASE(13) KCASE(14) KCASE(15)
    KCASE(16) KCASE(17) KCASE(18) KCASE(19) KCASE(20) KCASE(21) KCASE(22) KCASE(23)
    KCASE(24) KCASE(25) KCASE(26) KCASE(27) KCASE(28) KCASE(29) KCASE(30)
#undef KCASE
  }
}

// ---- K2: per (row, head): N_m = sum_alpha C_a q^a S[a+u_m]; normalize,
//      exchange heads via LDS, 8x8 out-projection + bias ----
__global__ __launch_bounds__(256)
void qout_kernel(const float* __restrict__ x, const float* __restrict__ theta,
                 const float* __restrict__ ws, const float* __restrict__ w_out,
                 const float* __restrict__ b_out, float* __restrict__ out){
  __shared__ float po[128 * 8];
  const int t   = (int)threadIdx.x;
  const int blk = (int)blockIdx.x;     // [b(16)][sb(16)]
  const int b   = blk >> 4;
  const int s0  = (blk & 15) << 7;
  const int lane = t & 63;
  const int h  = __builtin_amdgcn_readfirstlane((t >> 6) & 1);  // wave-uniform
  const int rr = ((t >> 7) << 6) | lane;                        // 0..127
  const int s  = s0 + rr;

  const float4 th = ((const float4*)theta)[h];
  float4 xr = ((const float4*)x)[(size_t)(b*SS+s)*2 + h];
  const float q0 = __cosf(xr.x + th.x), q1 = __cosf(xr.y + th.y),
              q2 = __cosf(xr.z + th.z), q3 = __cosf(xr.w + th.w);
  float p0[8], p1[8], p2[8], p3[8];
  p0[0]=1.f; p1[0]=1.f; p2[0]=1.f; p3[0]=1.f;
#pragma unroll
  for (int e=1;e<8;++e){
    p0[e]=p0[e-1]*q0; p1[e]=p1[e-1]*q1; p2[e]=p2[e-1]*q2; p3[e]=p3[e-1]*q3;
  }
  const float* Sp = ws + (size_t)((b<<1) + h) * SPAD;   // uniform -> s_load
  float n0=0.f, n1=0.f, n2=0.f, n3=0.f, dn=0.f;
#pragma unroll
  for (int F=0; F<NF; ++F){
    const E4 e = TAB.fe[F];             // constexpr -> folds after unroll
    const float m = p0[e.e0]*p1[e.e1]*p2[e.e2]*p3[e.e3]*TAB.fc[F];
    n0 = fmaf(m, Sp[TAB.sidx[F][0]], n0);
    n1 = fmaf(m, Sp[TAB.sidx[F][1]], n1);
    n2 = fmaf(m, Sp[TAB.sidx[F][2]], n2);
    n3 = fmaf(m, Sp[TAB.sidx[F][3]], n3);
    dn = fmaf(m, Sp[TAB.sidx[F][4]], dn);
  }
  const float inv = 1.0f / dn;
  po[rr*8 + h*4 + 0] = n0*inv;
  po[rr*8 + h*4 + 1] = n1*inv;
  po[rr*8 + h*4 + 2] = n2*inv;
  po[rr*8 + h*4 + 3] = n3*inv;
  __syncthreads();

  if (t < 128){
    const float* pr = po + t*8;
    float o[8];
#pragma unroll
    for (int j=0;j<8;++j) o[j] = pr[j];
    float r[8];
#pragma unroll
    for (int e=0;e<8;++e){
      float acc = b_out[e];
#pragma unroll
      for (int j=0;j<8;++j) acc = fmaf(o[j], w_out[e*8+j], acc);
      r[e] = acc;
    }
    float* op = out + ((size_t)(b*SS + s0 + t)) * 8;
    *(float4*)op       = make_float4(r[0], r[1], r[2], r[3]);
    *(float4*)(op + 4) = make_float4(r[4], r[5], r[6], r[7]);
  }
}

extern "C" void kernel_launch(void* const* d_in, const int* in_sizes, int n_in,
                              void* d_out, int out_size, void* d_ws, size_t ws_size,
                              hipStream_t stream) {
  const float* x     = (const float*)d_in[0];
  const float* theta = (const float*)d_in[1];
  const float* w_out = (const float*)d_in[2];
  const float* b_out = (const float*)d_in[3];
  float* out = (float*)d_out;
  (void)in_sizes; (void)n_in; (void)out_size; (void)ws_size;

  // ws: 32 (b,h) x 512 floats of power sums, atomically accumulated -> zero it
  (void)hipMemsetAsync(d_ws, 0, (size_t)32 * SPAD * sizeof(float), stream);
  qsum_kernel<<<dim3(32 * 32), 256, 0, stream>>>(x, theta, (float*)d_ws);
  qout_kernel<<<dim3(BB * 16), 256, 0, stream>>>(x, theta, (const float*)d_ws,
                                                 w_out, b_out, out);
}

// Round 11
// 83.381 us; speedup vs baseline: 1.0662x; 1.0662x over previous
//
#include <hip/hip_runtime.h>
#include <utility>
#include <math.h>

#define BB 16
#define SS 2048
#define NF 210        // features: monomials deg<=6 in 4 vars
#define NS 330        // power sums: deg<=7
#define SSTR 336      // S stride per (b,h) in floats
#define GSTR 224      // per-m stride inside G block
#define GBH (5*GSTR)  // 1120 floats per (b,h)
#define GBASE 16384   // float offset of G region in ws
#define NTILE 21      // ceil(330/16)

struct E4 { int e0, e1, e2, e3; };

constexpr E4 exp_at(int idx, int deg) {
  int r = 0;
  for (int a = 0; a <= deg; ++a)
    for (int b = 0; b <= deg - a; ++b)
      for (int c = 0; c <= deg - a - b; ++c)
        for (int d = 0; d <= deg - a - b - c; ++d) {
          if (r == idx) return E4{a, b, c, d};
          ++r;
        }
  return E4{0, 0, 0, 0};
}
constexpr int rank_of(int a, int b, int c, int d, int deg) {
  int r = 0;
  for (int aa = 0; aa <= deg; ++aa)
    for (int bb = 0; bb <= deg - aa; ++bb)
      for (int cc = 0; cc <= deg - aa - bb; ++cc)
        for (int dd = 0; dd <= deg - aa - bb - cc; ++dd) {
          if (aa == a && bb == b && cc == c && dd == d) return r;
          ++r;
        }
  return 0;
}
constexpr double besselI2(int n) {          // I_n(2) = sum 1/(m!(m+n)!)
  double t = 1.0;
  for (int i = 1; i <= n; ++i) t /= (double)i;
  double s = 0.0;
  for (int m = 0; m < 16; ++m) { if (m > 0) t /= (double)(m * (m + n)); s += t; }
  return s;
}

struct FTab { int sidx[NF][5]; float fc[NF]; };
constexpr FTab gen_ftab() {
  FTab T{};
  double cheb[7] = {};
  for (int n = 0; n < 7; ++n) cheb[n] = (n == 0 ? 1.0 : 2.0) * besselI2(n);
  const int tm[7][7] = {
    {1,0,0,0,0,0,0},{0,1,0,0,0,0,0},{-1,0,2,0,0,0,0},{0,-3,0,4,0,0,0},
    {1,0,-8,0,8,0,0},{0,5,0,-20,0,16,0},{-1,0,18,0,-48,0,32}};
  double bk[7] = {};
  double p2 = 1.0;
  for (int k = 0; k < 7; ++k) {
    double tc = 0.0;
    for (int n = 0; n < 7; ++n) tc += cheb[n] * (double)tm[n][k];
    bk[k] = tc / p2;                        // t = s/2 -> extra /2^k
    p2 *= 2.0;
  }
  const double fact[8] = {1,1,2,6,24,120,720,5040};
  int idx = 0;
  for (int a = 0; a <= 6; ++a)
    for (int b = 0; b <= 6 - a; ++b)
      for (int c = 0; c <= 6 - a - b; ++c)
        for (int d = 0; d <= 6 - a - b - c; ++d) {
          const int k = a + b + c + d;
          const double mult = fact[k] / (fact[a]*fact[b]*fact[c]*fact[d]);
          double pk = 1.0; for (int i = 0; i < k; ++i) pk *= 2.0;
          T.fc[idx] = (float)(bk[k] * mult / pk);   // score = q.k/2
          T.sidx[idx][0] = rank_of(a+1, b, c, d, 7);
          T.sidx[idx][1] = rank_of(a, b+1, c, d, 7);
          T.sidx[idx][2] = rank_of(a, b, c+1, d, 7);
          T.sidx[idx][3] = rank_of(a, b, c, d+1, 7);
          T.sidx[idx][4] = rank_of(a, b, c, d, 7);
          ++idx;
        }
  return T;
}
__constant__ constexpr FTab FT = gen_ftab();

// ---------------- K1: power sums S_beta (|beta|<=7) per (b,h) ----------------
template<int IDX, int SLOT>
__device__ __forceinline__ void acc_one(float* acc, const float* p0, const float* p1,
                                        const float* p2, const float* p3) {
  if constexpr (IDX < NS) {
    constexpr E4 e = exp_at(IDX, 7);        // AST-level constant
    acc[SLOT] += p0[e.e0] * p1[e.e1] * p2[e.e2] * p3[e.e3];
  }
}
template<int T, int... I>
__device__ __forceinline__ void acc_tile(float* acc, const float* p0, const float* p1,
                                         const float* p2, const float* p3,
                                         std::integer_sequence<int, I...>) {
  (acc_one<T * 16 + I, I>(acc, p0, p1, p2, p3), ...);
}
template<int IDX, int SLOT>
__device__ __forceinline__ void red_one(float* acc, int lane, float* wsbh) {
  if constexpr (IDX < NS) {
    float v = acc[SLOT];
    v += __shfl_xor(v, 1, 64);  v += __shfl_xor(v, 2, 64);
    v += __shfl_xor(v, 4, 64);  v += __shfl_xor(v, 8, 64);
    v += __shfl_xor(v, 16, 64); v += __shfl_xor(v, 32, 64);
    if (lane == 0) atomicAdd(wsbh + IDX, v);
  }
}
template<int T, int... I>
__device__ __forceinline__ void red_tile(float* acc, int lane, float* wsbh,
                                         std::integer_sequence<int, I...>) {
  (red_one<T * 16 + I, I>(acc, lane, wsbh), ...);
}
template<int T>
__device__ __forceinline__ void sum_tile(const float4* x4, float4 th, int b, int h,
                                         int t, float* wsbh) {
  float acc[16];
#pragma unroll
  for (int i = 0; i < 16; ++i) acc[i] = 0.f;
  for (int rr = 0; rr < 8; ++rr) {
    const int s = (rr << 8) + t;
    float4 xr = x4[(size_t)(b * SS + s) * 2 + h];
    const float q0 = __cosf(xr.x + th.x), q1 = __cosf(xr.y + th.y),
                q2 = __cosf(xr.z + th.z), q3 = __cosf(xr.w + th.w);
    float p0[8], p1[8], p2[8], p3[8];
    p0[0] = 1.f; p1[0] = 1.f; p2[0] = 1.f; p3[0] = 1.f;
#pragma unroll
    for (int e = 1; e < 8; ++e) {
      p0[e] = p0[e-1] * q0; p1[e] = p1[e-1] * q1;
      p2[e] = p2[e-1] * q2; p3[e] = p3[e-1] * q3;
    }
    acc_tile<T>(acc, p0, p1, p2, p3, std::make_integer_sequence<int, 16>{});
  }
  red_tile<T>(acc, (int)(threadIdx.x & 63), wsbh, std::make_integer_sequence<int, 16>{});
}

__global__ __launch_bounds__(256)
void qsum_kernel(const float* __restrict__ x, const float* __restrict__ theta,
                 float* __restrict__ ws) {
  const int tile = (int)blockIdx.x;   // 0..20
  const int bh   = (int)blockIdx.y;   // 0..31
  const int b = bh >> 1, h = bh & 1;
  const int t = (int)threadIdx.x;
  const float4 th = ((const float4*)theta)[h];
  const float4* x4 = (const float4*)x;
  float* wsbh = ws + (size_t)bh * SSTR;
  switch (tile) {
#define KC(n) case n: sum_tile<n>(x4, th, b, h, t, wsbh); break;
    KC(0) KC(1) KC(2) KC(3) KC(4) KC(5) KC(6) KC(7) KC(8) KC(9) KC(10)
    KC(11) KC(12) KC(13) KC(14) KC(15) KC(16) KC(17) KC(18) KC(19) KC(20)
#undef KC
  }
}

// ---------- KG: G[bh][m][F] = C_F * S[F + u_m]  (coefficient folded) ----------
__global__ __launch_bounds__(256)
void qg_kernel(const float* __restrict__ ws, float* __restrict__ wsg) {
  const int bh = (int)blockIdx.x;
  const int F  = (int)threadIdx.x;
  if (F >= NF) return;
  const float* Sp = ws + (size_t)bh * SSTR;
  float* Gp = wsg + (size_t)bh * GBH;
  const float c = FT.fc[F];
  Gp[0 * GSTR + F] = c * Sp[FT.sidx[F][0]];
  Gp[1 * GSTR + F] = c * Sp[FT.sidx[F][1]];
  Gp[2 * GSTR + F] = c * Sp[FT.sidx[F][2]];
  Gp[3 * GSTR + F] = c * Sp[FT.sidx[F][3]];
  Gp[4 * GSTR + F] = c * Sp[FT.sidx[F][4]];
}

// ---- K2: per (row,head): 210-term dot vs 5 G-columns; normalize; project ----
template<int F>
__device__ __forceinline__ void feat_one(float* n, const float* __restrict__ Gp,
                                         const float* p0, const float* p1,
                                         const float* p2, const float* p3) {
  constexpr E4 e = exp_at(F, 6);            // AST-level constant
  const float m = p0[e.e0] * p1[e.e1] * p2[e.e2] * p3[e.e3];
  n[0] = fmaf(m, Gp[0 * GSTR + F], n[0]);
  n[1] = fmaf(m, Gp[1 * GSTR + F], n[1]);
  n[2] = fmaf(m, Gp[2 * GSTR + F], n[2]);
  n[3] = fmaf(m, Gp[3 * GSTR + F], n[3]);
  n[4] = fmaf(m, Gp[4 * GSTR + F], n[4]);
}
template<int... F>
__device__ __forceinline__ void feat_all(float* n, const float* __restrict__ Gp,
                                         const float* p0, const float* p1,
                                         const float* p2, const float* p3,
                                         std::integer_sequence<int, F...>) {
  (feat_one<F>(n, Gp, p0, p1, p2, p3), ...);
}

__global__ __launch_bounds__(256)
void qout_kernel(const float* __restrict__ x, const float* __restrict__ theta,
                 const float* __restrict__ wsg, const float* __restrict__ w_out,
                 const float* __restrict__ b_out, float* __restrict__ out) {
  __shared__ float po[128 * 8];
  const int t   = (int)threadIdx.x;
  const int blk = (int)blockIdx.x;          // [b(16)][sb(16)]
  const int b   = blk >> 4;
  const int s0  = (blk & 15) << 7;
  const int lane = t & 63;
  const int h  = __builtin_amdgcn_readfirstlane((t >> 6) & 1);  // wave-uniform
  const int rr = ((t >> 7) << 6) | lane;                        // 0..127
  const int s  = s0 + rr;

  const float4 th = ((const float4*)theta)[h];
  float4 xr = ((const float4*)x)[(size_t)(b * SS + s) * 2 + h];
  const float q0 = __cosf(xr.x + th.x), q1 = __cosf(xr.y + th.y),
              q2 = __cosf(xr.z + th.z), q3 = __cosf(xr.w + th.w);
  float p0[7], p1[7], p2[7], p3[7];
  p0[0] = 1.f; p1[0] = 1.f; p2[0] = 1.f; p3[0] = 1.f;
#pragma unroll
  for (int e = 1; e < 7; ++e) {
    p0[e] = p0[e-1] * q0; p1[e] = p1[e-1] * q1;
    p2[e] = p2[e-1] * q2; p3[e] = p3[e-1] * q3;
  }
  const float* Gp = wsg + (size_t)((b << 1) + h) * GBH;   // wave-uniform
  float n[5] = {0.f, 0.f, 0.f, 0.f, 0.f};
  feat_all(n, Gp, p0, p1, p2, p3, std::make_integer_sequence<int, NF>{});

  const float inv = 1.0f / n[4];
  po[rr * 8 + h * 4 + 0] = n[0] * inv;
  po[rr * 8 + h * 4 + 1] = n[1] * inv;
  po[rr * 8 + h * 4 + 2] = n[2] * inv;
  po[rr * 8 + h * 4 + 3] = n[3] * inv;
  __syncthreads();

  if (t < 128) {
    const float* pr = po + t * 8;
    float o[8];
#pragma unroll
    for (int j = 0; j < 8; ++j) o[j] = pr[j];
    float r[8];
#pragma unroll
    for (int e = 0; e < 8; ++e) {
      float acc = b_out[e];
#pragma unroll
      for (int j = 0; j < 8; ++j) acc = fmaf(o[j], w_out[e * 8 + j], acc);
      r[e] = acc;
    }
    float* op = out + ((size_t)(b * SS + s0 + t)) * 8;
    *(float4*)op       = make_float4(r[0], r[1], r[2], r[3]);
    *(float4*)(op + 4) = make_float4(r[4], r[5], r[6], r[7]);
  }
}

extern "C" void kernel_launch(void* const* d_in, const int* in_sizes, int n_in,
                              void* d_out, int out_size, void* d_ws, size_t ws_size,
                              hipStream_t stream) {
  const float* x     = (const float*)d_in[0];
  const float* theta = (const float*)d_in[1];
  const float* w_out = (const float*)d_in[2];
  const float* b_out = (const float*)d_in[3];
  float* out = (float*)d_out;
  float* ws  = (float*)d_ws;
  float* wsg = ws + GBASE;
  (void)in_sizes; (void)n_in; (void)out_size; (void)ws_size;

  // S region (32 x 336 floats) is atomically accumulated -> zero it first
  (void)hipMemsetAsync(d_ws, 0, (size_t)32 * SSTR * sizeof(float), stream);
  qsum_kernel<<<dim3(NTILE, 32), 256, 0, stream>>>(x, theta, ws);
  qg_kernel<<<dim3(32), 256, 0, stream>>>(ws, wsg);
  qout_kernel<<<dim3(BB * 16), 256, 0, stream>>>(x, theta, wsg, w_out, b_out, out);
}